// Round 8
// baseline (258.476 us; speedup 1.0000x reference)
//
#include <hip/hip_runtime.h>

// Problem constants (B,H,W,C = 8,64,64,256; S = H*W)
#define NB   8
#define SS   4096
#define CC   256
#define NG   32
#define CPG  8
#define EPSV 1e-6f
#define MTOT (NB * SS)   // 32768 rows

typedef short bf16x8 __attribute__((ext_vector_type(8)));
typedef unsigned short u16x8 __attribute__((ext_vector_type(8)));
typedef float f32x4  __attribute__((ext_vector_type(4)));
typedef float f32x16 __attribute__((ext_vector_type(16)));
typedef int   i32x4  __attribute__((ext_vector_type(4)));
typedef int   i32x8  __attribute__((ext_vector_type(8)));
typedef unsigned char u8;

typedef __attribute__((address_space(1))) const unsigned int as1_u32;
typedef __attribute__((address_space(3))) unsigned int as3_u32;

__device__ __forceinline__ unsigned short f2bf(float f) {
  unsigned int u = __builtin_bit_cast(unsigned int, f);
  u = (u + 0x7FFFu + ((u >> 16) & 1u)) >> 16;
  return (unsigned short)u;
}
__device__ __forceinline__ u8 f2fp8(float f) {
  return (u8)(__builtin_amdgcn_cvt_pk_fp8_f32(f, f, 0, 0) & 0xFF);
}
__device__ __forceinline__ void dma16(const u8* src, u8* lds) {
  __builtin_amdgcn_global_load_lds((as1_u32*)src, (as3_u32*)lds, 16, 0, 0);
}
__device__ __forceinline__ float fast_exp2(float x) {
#if __has_builtin(__builtin_amdgcn_exp2f)
  return __builtin_amdgcn_exp2f(x);   // bare v_exp_f32
#else
  return exp2f(x);
#endif
}

// ---------------- GroupNorm stats, stage 1: coalesced partials ----------------
__global__ __launch_bounds__(256) void gn_stats_part_kernel(
    const float* __restrict__ x, float* __restrict__ part) {
  const int b = blockIdx.x >> 5, slice = blockIdx.x & 31;
  const int tid = threadIdx.x;
  const int g = tid & 31;            // group
  const int p8 = tid >> 5;           // pos sub-index 0..7
  const float* base = x + ((size_t)(b * SS + slice * 128 + p8) * CC + g * CPG);
  float s = 0.f, ss = 0.f;
#pragma unroll
  for (int it = 0; it < 16; it++) {
    const float4* p = (const float4*)(base + (size_t)it * 8 * CC);
    float4 a = p[0], c = p[1];
    s  += (a.x + a.y) + (a.z + a.w) + (c.x + c.y) + (c.z + c.w);
    ss += (a.x*a.x + a.y*a.y) + (a.z*a.z + a.w*a.w)
        + (c.x*c.x + c.y*c.y) + (c.z*c.z + c.w*c.w);
  }
  s  += __shfl_xor(s, 32);
  ss += __shfl_xor(ss, 32);
  __shared__ float lsum[4][32], lssum[4][32];
  const int wv = tid >> 6, lane = tid & 63;
  if (lane < 32) { lsum[wv][lane] = s; lssum[wv][lane] = ss; }
  __syncthreads();
  if (tid < 32) {
    float ts  = (lsum[0][tid] + lsum[1][tid]) + (lsum[2][tid] + lsum[3][tid]);
    float tss = (lssum[0][tid] + lssum[1][tid]) + (lssum[2][tid] + lssum[3][tid]);
    float* dst = part + ((size_t)(b * 32 + tid) * 32 + slice) * 2;
    dst[0] = ts; dst[1] = tss;
  }
}

// ---------------- Weight prep (+ fused gn_stats finalize at y==4) ----------------
__global__ __launch_bounds__(256) void prep_wt_kernel(
    const float* __restrict__ w0, const float* __restrict__ w1,
    const float* __restrict__ w2, const float* __restrict__ w3,
    unsigned short* __restrict__ wt,
    const float* __restrict__ part, float* __restrict__ stats) {
  __shared__ float t[64][68];
  if (blockIdx.y == 4) {
    if (blockIdx.x == 0) {
      const int bg = threadIdx.x;   // b*32+g, 0..255
      const float* src = part + (size_t)bg * 64;
      float s = 0.f, ss = 0.f;
#pragma unroll
      for (int sl = 0; sl < 32; sl++) { s += src[sl * 2]; ss += src[sl * 2 + 1]; }
      const float inv = 1.f / (float)(SS * CPG);
      float mean = s * inv;
      float var  = ss * inv - mean * mean;
      stats[bg * 2]     = mean;
      stats[bg * 2 + 1] = rsqrtf(var + EPSV);
    }
    return;
  }
  int which = blockIdx.y;
  const float* W = (which == 0) ? w0 : (which == 1) ? w1 : (which == 2) ? w2 : w3;
  int tx = (blockIdx.x & 3) * 64;
  int ty = (blockIdx.x >> 2) * 64;
  int tid = threadIdx.x;
  int row = tid >> 4;
  int col = (tid & 15) * 4;
#pragma unroll
  for (int i = 0; i < 4; i++) {
    float4 v = *(const float4*)(W + (size_t)(ty + row + i * 16) * CC + tx + col);
    *(float4*)(&t[row + i * 16][col]) = v;
  }
  __syncthreads();
#pragma unroll
  for (int i = 0; i < 4; i++) {
    int n = row + i * 16;
    ushort4 o;
    o.x = f2bf(t[col + 0][n]);
    o.y = f2bf(t[col + 1][n]);
    o.z = f2bf(t[col + 2][n]);
    o.w = f2bf(t[col + 3][n]);
    *(ushort4*)(wt + (size_t)which * CC * CC + (size_t)(tx + n) * CC + ty + col) = o;
  }
}

// ---------------- GroupNorm: normalize -> hn (bf16), 8 ch/thread ----------------
__global__ __launch_bounds__(256) void gn_norm_kernel(const float* __restrict__ x,
                                                      const float* __restrict__ stats,
                                                      const float* __restrict__ gamma,
                                                      const float* __restrict__ beta,
                                                      unsigned short* __restrict__ hn) {
  int i8 = blockIdx.x * 256 + threadIdx.x;
  int c8 = (i8 & 31) * 8;
  size_t row = (size_t)(i8 >> 5);
  int b = (int)(row >> 12);
  int sidx = (b * NG + (c8 >> 3)) * 2;
  float mean = stats[sidx], rstd = stats[sidx + 1];
  const float4* xp = (const float4*)(x + row * CC + c8);
  float4 v0 = xp[0], v1 = xp[1];
  const float4* gp = (const float4*)(gamma + c8);
  float4 g0 = gp[0], g1 = gp[1];
  const float4* bp = (const float4*)(beta + c8);
  float4 b0 = bp[0], b1 = bp[1];
  u16x8 o;
  o[0] = f2bf((v0.x - mean) * rstd * g0.x + b0.x);
  o[1] = f2bf((v0.y - mean) * rstd * g0.y + b0.y);
  o[2] = f2bf((v0.z - mean) * rstd * g0.z + b0.z);
  o[3] = f2bf((v0.w - mean) * rstd * g0.w + b0.w);
  o[4] = f2bf((v1.x - mean) * rstd * g1.x + b1.x);
  o[5] = f2bf((v1.y - mean) * rstd * g1.y + b1.y);
  o[6] = f2bf((v1.z - mean) * rstd * g1.z + b1.z);
  o[7] = f2bf((v1.w - mean) * rstd * g1.w + b1.w);
  *(u16x8*)(hn + row * CC + c8) = o;
}

// ---------------- GEMM v2: B-slab resident + A dbuf via global_load_lds ----------------
// Tile 256(m) x 64(n), K-step 32, 4 waves each 64x64. 1 barrier per K-step.

// QKV fused. Outputs: q fp8 (B,S,C) unscaled, k fp8 (B,S,C), v fp8 TRANSPOSED (B,C,S).
__global__ __launch_bounds__(256) void qkv_gemm_kernel(
    const unsigned short* __restrict__ A,
    const unsigned short* __restrict__ WT,
    const float* __restrict__ bq, const float* __restrict__ bk, const float* __restrict__ bv,
    u8* __restrict__ qo, u8* __restrict__ ko, u8* __restrict__ vt) {
  __shared__ __align__(1024) u8 smem[65536];
  u8* As0 = smem;            // 16KB
  u8* As1 = smem + 16384;    // 16KB
  u8* Bs  = smem + 32768;    // 32KB

  const int which = blockIdx.z;
  const u8* Bwb = (const u8*)(WT + (size_t)which * CC * CC);
  const float* bias = (which == 0) ? bq : (which == 1) ? bk : bv;

  const int m0 = blockIdx.x * 256;
  const int n0 = blockIdx.y * 64;
  const int tid = threadIdx.x;
  const int wave = tid >> 6, lane = tid & 63;
  const int l32 = lane & 31, h = lane >> 5;

  const u8* Ab = (const u8*)A;

  const int am = tid >> 2;
  const int aslot = tid & 3;
  const size_t asrc_row = (size_t)(m0 + am) * 512;
  const int asrc_ch = ((aslot ^ (am & 3)) << 4);
  const int bn = tid >> 5;
  const int bslot = tid & 31;

#pragma unroll
  for (int i = 0; i < 8; i++) {
    int n = i * 8 + bn;
    dma16(Bwb + (size_t)(n0 + n) * 512 + ((bslot ^ (n & 31)) << 4),
          Bs + i * 4096 + tid * 16);
  }
#pragma unroll
  for (int i = 0; i < 4; i++)
    dma16(Ab + asrc_row + (size_t)i * 64 * 512 + asrc_ch, As0 + i * 4096 + tid * 16);
  __syncthreads();

  f32x16 acc[2][2] = {};
  const int arow0 = (wave * 64 + l32) * 64;
  const int nrow0 = l32 * 512;
  const int aswz = l32 & 3;
  const int bswz = l32;

#pragma unroll
  for (int s = 0; s < 8; ++s) {
    u8* cur = (s & 1) ? As1 : As0;
    if (s < 7) {
      u8* nxt = (s & 1) ? As0 : As1;
      size_t koff = (size_t)(s + 1) * 64;
#pragma unroll
      for (int i = 0; i < 4; i++)
        dma16(Ab + asrc_row + (size_t)i * 64 * 512 + koff + asrc_ch,
              nxt + i * 4096 + tid * 16);
    }
#pragma unroll
    for (int ks = 0; ks < 2; ks++) {
      bf16x8 af0 = *(const bf16x8*)(cur + arow0 + (((h + 2 * ks) ^ aswz) << 4));
      bf16x8 af1 = *(const bf16x8*)(cur + arow0 + 32 * 64 + (((h + 2 * ks) ^ aswz) << 4));
      bf16x8 bf0 = *(const bf16x8*)(Bs + nrow0 + (((s * 4 + h + 2 * ks) ^ bswz) << 4));
      bf16x8 bf1 = *(const bf16x8*)(Bs + nrow0 + 32 * 512 + (((s * 4 + h + 2 * ks) ^ bswz) << 4));
      acc[0][0] = __builtin_amdgcn_mfma_f32_32x32x16_bf16(af0, bf0, acc[0][0], 0, 0, 0);
      acc[0][1] = __builtin_amdgcn_mfma_f32_32x32x16_bf16(af0, bf1, acc[0][1], 0, 0, 0);
      acc[1][0] = __builtin_amdgcn_mfma_f32_32x32x16_bf16(af1, bf0, acc[1][0], 0, 0, 0);
      acc[1][1] = __builtin_amdgcn_mfma_f32_32x32x16_bf16(af1, bf1, acc[1][1], 0, 0, 0);
    }
    __syncthreads();
  }

  if (which < 2) {
    u8* out = (which == 0) ? qo : ko;
#pragma unroll
    for (int nt = 0; nt < 2; nt++) {
      int n = n0 + nt * 32 + l32;
      float bv_ = bias[n];
#pragma unroll
      for (int mt = 0; mt < 2; mt++)
#pragma unroll
        for (int r = 0; r < 16; r++) {
          int m = m0 + wave * 64 + mt * 32 + (r & 3) + 8 * (r >> 2) + 4 * h;
          out[(size_t)m * CC + n] = f2fp8(acc[mt][nt][r] + bv_);
        }
    }
  } else {
    int bb = m0 >> 12;
#pragma unroll
    for (int nt = 0; nt < 2; nt++) {
      int n = n0 + nt * 32 + l32;
      float bv_ = bias[n];
#pragma unroll
      for (int mt = 0; mt < 2; mt++)
#pragma unroll
        for (int g = 0; g < 4; g++) {
          int mg = m0 + wave * 64 + mt * 32 + g * 8 + 4 * h;
          int w = __builtin_amdgcn_cvt_pk_fp8_f32(acc[mt][nt][g*4+0] + bv_, acc[mt][nt][g*4+1] + bv_, 0, 0);
          w = __builtin_amdgcn_cvt_pk_fp8_f32(acc[mt][nt][g*4+2] + bv_, acc[mt][nt][g*4+3] + bv_, w, 1);
          *(unsigned int*)(vt + (size_t)bb * CC * SS + (size_t)n * SS + (mg & 4095)) = (unsigned int)w;
        }
    }
  }
}

// Final projection: out = ao @ wo + bo + x  (fp32 out)
__global__ __launch_bounds__(256) void out_gemm_kernel(
    const unsigned short* __restrict__ A,
    const unsigned short* __restrict__ WT,
    const float* __restrict__ bias,
    const float* __restrict__ residual,
    float* __restrict__ Of) {
  __shared__ __align__(1024) u8 smem[65536];
  u8* As0 = smem;
  u8* As1 = smem + 16384;
  u8* Bs  = smem + 32768;

  const u8* Bwb = (const u8*)(WT + (size_t)3 * CC * CC);
  const int m0 = blockIdx.x * 256;
  const int n0 = blockIdx.y * 64;
  const int tid = threadIdx.x;
  const int wave = tid >> 6, lane = tid & 63;
  const int l32 = lane & 31, h = lane >> 5;

  const u8* Ab = (const u8*)A;
  const int am = tid >> 2;
  const int aslot = tid & 3;
  const size_t asrc_row = (size_t)(m0 + am) * 512;
  const int asrc_ch = ((aslot ^ (am & 3)) << 4);
  const int bn = tid >> 5;
  const int bslot = tid & 31;

#pragma unroll
  for (int i = 0; i < 8; i++) {
    int n = i * 8 + bn;
    dma16(Bwb + (size_t)(n0 + n) * 512 + ((bslot ^ (n & 31)) << 4),
          Bs + i * 4096 + tid * 16);
  }
#pragma unroll
  for (int i = 0; i < 4; i++)
    dma16(Ab + asrc_row + (size_t)i * 64 * 512 + asrc_ch, As0 + i * 4096 + tid * 16);
  __syncthreads();

  f32x16 acc[2][2] = {};
  const int arow0 = (wave * 64 + l32) * 64;
  const int nrow0 = l32 * 512;
  const int aswz = l32 & 3;
  const int bswz = l32;

#pragma unroll
  for (int s = 0; s < 8; ++s) {
    u8* cur = (s & 1) ? As1 : As0;
    if (s < 7) {
      u8* nxt = (s & 1) ? As0 : As1;
      size_t koff = (size_t)(s + 1) * 64;
#pragma unroll
      for (int i = 0; i < 4; i++)
        dma16(Ab + asrc_row + (size_t)i * 64 * 512 + koff + asrc_ch,
              nxt + i * 4096 + tid * 16);
    }
#pragma unroll
    for (int ks = 0; ks < 2; ks++) {
      bf16x8 af0 = *(const bf16x8*)(cur + arow0 + (((h + 2 * ks) ^ aswz) << 4));
      bf16x8 af1 = *(const bf16x8*)(cur + arow0 + 32 * 64 + (((h + 2 * ks) ^ aswz) << 4));
      bf16x8 bf0 = *(const bf16x8*)(Bs + nrow0 + (((s * 4 + h + 2 * ks) ^ bswz) << 4));
      bf16x8 bf1 = *(const bf16x8*)(Bs + nrow0 + 32 * 512 + (((s * 4 + h + 2 * ks) ^ bswz) << 4));
      acc[0][0] = __builtin_amdgcn_mfma_f32_32x32x16_bf16(af0, bf0, acc[0][0], 0, 0, 0);
      acc[0][1] = __builtin_amdgcn_mfma_f32_32x32x16_bf16(af0, bf1, acc[0][1], 0, 0, 0);
      acc[1][0] = __builtin_amdgcn_mfma_f32_32x32x16_bf16(af1, bf0, acc[1][0], 0, 0, 0);
      acc[1][1] = __builtin_amdgcn_mfma_f32_32x32x16_bf16(af1, bf1, acc[1][1], 0, 0, 0);
    }
    __syncthreads();
  }

#pragma unroll
  for (int nt = 0; nt < 2; nt++) {
    int n = n0 + nt * 32 + l32;
    float bv_ = bias[n];
#pragma unroll
    for (int mt = 0; mt < 2; mt++)
#pragma unroll
      for (int r = 0; r < 16; r++) {
        int m = m0 + wave * 64 + mt * 32 + (r & 3) + 8 * (r >> 2) + 4 * h;
        Of[(size_t)m * CC + n] = acc[mt][nt][r] + bv_ + residual[(size_t)m * CC + n];
      }
  }
}

// ---------------- Flash attention v6: key-split blocks + channel-split PV ----------------
// Grid 1024 = 8 b x 64 qtiles x 2 ksplit; each block does 2048 keys and emits
// UNNORMALIZED partial O (bf16) + partial l (f32). No running max (fixed clamp)
// -> partials combine exactly in combine_kernel.
// LDS 41KB: K single-buffer 16K (dbuf unnecessary: K(j+1) DMA issues after
// barrier Y where K(j) reads are done, drains at next X) + V 16K + Ps 8.5K
// (row stride 136B: bank base 2*row mod 32 -> full row entropy, ~2-way) + Lred.
// 3 blocks/CU by LDS, 3 waves/SIMD by regs (148 <= 170) -> 12 waves/CU.
#define BR 64

__global__ __launch_bounds__(256, 3) void flash_attn_kernel(
    const u8* __restrict__ Qg,   // (B,S,C) fp8, unscaled
    const u8* __restrict__ Kg,   // (B,S,C) fp8
    const u8* __restrict__ Vtg,  // (B,C,S) fp8
    unsigned short* __restrict__ po0,   // partial O, ks=0 (B,S,C) bf16 unnormalized
    unsigned short* __restrict__ po1,   // partial O, ks=1
    float* __restrict__ pl) {           // partial l: [2][MTOT] f32
  // [0,16384) K [64][256] | [16384,32768) V [256][64]
  // [32768,41472) Ps[64][136] | [41472,41984) Lred[2][64]
  __shared__ __align__(1024) u8 smem[41984];
  u8* KB = smem;
  u8* VB = smem + 16384;
  u8* Ps = smem + 32768;
  float* Lred = (float*)(smem + 41472);

  const int bid = blockIdx.x;
  const int b = bid & 7, q0 = ((bid >> 3) & 63) * BR, ks = bid >> 9;
  const int tid = threadIdx.x;
  const int wave = tid >> 6, lane = tid & 63;
  const int l32 = lane & 31, h = lane >> 5;
  const int wm = wave >> 1, wc = wave & 1;   // wm: q-row half, wc: key half (QK) / ch half (PV)

  const u8* Qb  = Qg  + (size_t)b * SS * CC;
  const u8* Kb  = Kg  + (size_t)b * SS * CC;
  const u8* Vtb = Vtg + (size_t)b * CC * SS;

  // K DMA: issue i -> key = i*16 + (tid>>4), chunk16 = tid&15; LDS[k][c]=K[k][c^(k&15)]
  const int kkey = tid >> 4, kc16 = tid & 15;
  const u8* ksrc0 = Kb + (size_t)kkey * CC + ((kc16 ^ (kkey & 15)) << 4);
  // V DMA: issue i -> ch = i*64 + (tid>>2), chunk16 = tid&3; LDS[ch][c]=V[ch][c^(ch&3)]
  const int vch = tid >> 2;
  const int vs  = (tid & 3) ^ (vch & 3);
  const u8* vsrc0 = Vtb + (size_t)vch * SS + (vs << 4);

  // Q B-frags (persistent): lane col = q-row wm*32+l32, k = t*64 + h*32 + [0..31]
  i32x8 qf[4];
  {
    const u8* qrow = Qb + (size_t)(q0 + wm * 32 + l32) * CC + h * 32;
#pragma unroll
    for (int t = 0; t < 4; t++) qf[t] = *(const i32x8*)(qrow + t * 64);
  }

  f32x16 oacc[4] = {};   // ch wc*128 + nt*32 + l32, summed over this block's keys
  float ll = 0.f;

  const int j0 = ks * 32;   // this block's first 64-key tile

  // prologue: K tile j0 -> KB (drained at first barrier X)
#pragma unroll
  for (int i = 0; i < 4; i++)
    dma16(ksrc0 + ((size_t)j0 * 64 + (size_t)i * 16) * CC, KB + i * 4096 + tid * 16);

  const int kswz = l32 & 15;   // QK read: key = wc*32+l32 -> key&15 = l32&15
  const int vswz = l32 & 3;    // PV read: ch & 3 = l32&3
  const int pswz = l32 & 7;    // Ps: row = wm*32+l32 -> row&7 = l32&7

  for (int jt = 0; jt < 32; ++jt) {
    const int j = j0 + jt;

    __syncthreads();   // X: K(j) drained; PV(j-1) reads of VB/Ps done
    {
      size_t vbase = (size_t)j * 64;
#pragma unroll
      for (int i = 0; i < 4; i++)
        dma16(vsrc0 + (size_t)i * 64 * SS + vbase, VB + i * 4096 + tid * 16);
    }

    // ---- QK^T: A = K (lane=key wc*32+l32), B = Q (lane=row wm*32+l32) ----
    {
      f32x16 sacc = {};
      const u8* kb = KB + (wc * 32 + l32) * 256;
      __builtin_amdgcn_s_setprio(1);
#pragma unroll
      for (int t = 0; t < 4; t++) {
        i32x4 r0 = *(const i32x4*)(kb + (((t * 4 + 2 * h)     ^ kswz) << 4));
        i32x4 r1 = *(const i32x4*)(kb + (((t * 4 + 2 * h + 1) ^ kswz) << 4));
        i32x8 kf = __builtin_shufflevector(r0, r1, 0, 1, 2, 3, 4, 5, 6, 7);
        sacc = __builtin_amdgcn_mfma_scale_f32_32x32x64_f8f6f4(
            kf, qf[t], sacc, 0, 0, 0, 0x7F7F7F7F, 0, 0x7F7F7F7F);
      }
      __builtin_amdgcn_s_setprio(0);
      // softmax-lite p = exp2(s*c) clamped; P -> Ps (row stride 136B)
      u8* pb = Ps + (wm * 32 + l32) * 136;
#pragma unroll
      for (int g = 0; g < 4; g++) {
        float p0 = fast_exp2(fminf(sacc[g * 4 + 0] * 0.09016844f, 7.213475f));
        float p1 = fast_exp2(fminf(sacc[g * 4 + 1] * 0.09016844f, 7.213475f));
        float p2 = fast_exp2(fminf(sacc[g * 4 + 2] * 0.09016844f, 7.213475f));
        float p3 = fast_exp2(fminf(sacc[g * 4 + 3] * 0.09016844f, 7.213475f));
        ll += (p0 + p1) + (p2 + p3);
        int wv_ = __builtin_amdgcn_cvt_pk_fp8_f32(p0, p1, 0, 0);
        wv_ = __builtin_amdgcn_cvt_pk_fp8_f32(p2, p3, wv_, 1);
        *(unsigned int*)(pb + (((wc * 4 + g) ^ pswz) << 3) + 4 * h) = (unsigned int)wv_;
      }
    }

    __syncthreads();   // Y: V(j) drained; Ps visible; QK(j) K-reads done
    if (jt + 1 < 32) {  // K(j+1) -> same KB (safe post-Y); drains at next X
      size_t krow = (size_t)(j + 1) * 64;
#pragma unroll
      for (int i = 0; i < 4; i++)
        dma16(ksrc0 + (krow + (size_t)i * 16) * CC, KB + i * 4096 + tid * 16);
    }

    // ---- PV: A = P (lane=row, k = h*32+[0..31]), B = V (lane=ch) ----
    {
      unsigned long pf[4];
      const u8* pb = Ps + (wm * 32 + l32) * 136;
#pragma unroll
      for (int ki = 0; ki < 4; ki++)
        pf[ki] = *(const unsigned long*)(pb + (((4 * h + ki) ^ pswz) << 3));
      i32x8 pa;
#pragma unroll
      for (int ki = 0; ki < 4; ki++) {
        pa[2 * ki]     = (int)(unsigned int)pf[ki];
        pa[2 * ki + 1] = (int)(unsigned int)(pf[ki] >> 32);
      }
      __builtin_amdgcn_s_setprio(1);
#pragma unroll
      for (int nt = 0; nt < 4; nt++) {
        const u8* vb = VB + (wc * 128 + nt * 32 + l32) * 64;
        i32x4 r0 = *(const i32x4*)(vb + (((2 * h)     ^ vswz) << 4));
        i32x4 r1 = *(const i32x4*)(vb + (((2 * h + 1) ^ vswz) << 4));
        i32x8 vf = __builtin_shufflevector(r0, r1, 0, 1, 2, 3, 4, 5, 6, 7);
        oacc[nt] = __builtin_amdgcn_mfma_scale_f32_32x32x64_f8f6f4(
            pa, vf, oacc[nt], 0, 0, 0, 0x7F7F7F7F, 0, 0x7F7F7F7F);
      }
      __builtin_amdgcn_s_setprio(0);
    }
  }

  // ---- epilogue: row-sum across wc halves, write UNNORMALIZED partials ----
  ll += __shfl_xor(ll, 32);
  if (h == 0) Lred[wc * 64 + wm * 32 + l32] = ll;
  __syncthreads();

  unsigned short* po = (ks == 0) ? po0 : po1;
  if (tid < 64)
    pl[(size_t)ks * MTOT + (size_t)b * SS + q0 + tid] = Lred[tid] + Lred[64 + tid];

#pragma unroll
  for (int r = 0; r < 16; r++) {
    int row = (r & 3) + 8 * (r >> 2) + 4 * h;
    size_t base = ((size_t)b * SS + q0 + wm * 32 + row) * CC + wc * 128 + l32;
#pragma unroll
    for (int nt = 0; nt < 4; nt++)
      po[base + nt * 32] = f2bf(oacc[nt][r]);
  }
}

// ---------------- combine: ao = (po0 + po1) / (l0 + l1) ----------------
__global__ __launch_bounds__(256) void combine_kernel(
    const unsigned short* __restrict__ po0, const unsigned short* __restrict__ po1,
    const float* __restrict__ pl, unsigned short* __restrict__ ao) {
  int i8 = blockIdx.x * 256 + threadIdx.x;
  size_t row = (size_t)(i8 >> 5);
  float inv = 1.f / (pl[row] + pl[(size_t)MTOT + row]);
  u16x8 a  = *(const u16x8*)(po0 + (size_t)i8 * 8);
  u16x8 c  = *(const u16x8*)(po1 + (size_t)i8 * 8);
  u16x8 o;
#pragma unroll
  for (int t = 0; t < 8; t++) {
    float fa = __builtin_bit_cast(float, (unsigned int)a[t] << 16);
    float fc = __builtin_bit_cast(float, (unsigned int)c[t] << 16);
    o[t] = f2bf((fa + fc) * inv);
  }
  *(u16x8*)(ao + (size_t)i8 * 8) = o;
}

// ---------------- launch ----------------
extern "C" void kernel_launch(void* const* d_in, const int* in_sizes, int n_in,
                              void* d_out, int out_size, void* d_ws, size_t ws_size,
                              hipStream_t stream) {
  const float* x   = (const float*)d_in[0];
  const float* gsc = (const float*)d_in[1];
  const float* gbi = (const float*)d_in[2];
  const float* wq  = (const float*)d_in[3];
  const float* bq  = (const float*)d_in[4];
  const float* wk  = (const float*)d_in[5];
  const float* bk  = (const float*)d_in[6];
  const float* wv  = (const float*)d_in[7];
  const float* bv  = (const float*)d_in[8];
  const float* wo  = (const float*)d_in[9];
  const float* bo  = (const float*)d_in[10];
  float* out = (float*)d_out;

  // workspace: stats | wt(bf16) | hn(bf16) | ao(bf16) | q(fp8) | k(fp8) | vt(fp8) | pl(f32)
  char* ws = (char*)d_ws;
  const size_t MAT = (size_t)MTOT * CC;
  float* stats        = (float*)ws;
  unsigned short* wt  = (unsigned short*)(ws + 4096);
  unsigned short* hn  = wt + (size_t)4 * CC * CC;
  unsigned short* ao  = hn + MAT;
  u8* q  = (u8*)(ao + MAT);
  u8* k  = q + MAT;
  u8* vt = k + MAT;
  float* pl = (float*)(vt + MAT);   // 2*MTOT f32 = 256KB

  // aliases: gn partials use ao (dead before flash); flash po1 uses hn
  // (dead after qkv_gemm); flash po0 = ao (combine reads+rewrites in place).
  float* part = (float*)ao;

  gn_stats_part_kernel<<<NB * NG, 256, 0, stream>>>(x, part);
  prep_wt_kernel<<<dim3(16, 5), 256, 0, stream>>>(wq, wk, wv, wo, wt, part, stats);
  gn_norm_kernel<<<(int)(MAT / 8 / 256), 256, 0, stream>>>(x, stats, gsc, gbi, hn);

  qkv_gemm_kernel<<<dim3(MTOT / 256, CC / 64, 3), 256, 0, stream>>>(
      hn, wt, bq, bk, bv, q, k, vt);

  flash_attn_kernel<<<NB * (SS / BR) * 2, 256, 0, stream>>>(q, k, vt, ao, hn, pl);

  combine_kernel<<<(int)(MAT / 8 / 256), 256, 0, stream>>>(ao, hn, pl, ao);

  out_gemm_kernel<<<dim3(MTOT / 256, CC / 64), 256, 0, stream>>>(ao, wt, bo, x, out);
}

// Round 9
// 238.503 us; speedup vs baseline: 1.0837x; 1.0837x over previous
//
#include <hip/hip_runtime.h>

// Problem constants (B,H,W,C = 8,64,64,256; S = H*W)
#define NB   8
#define SS   4096
#define CC   256
#define NG   32
#define CPG  8
#define EPSV 1e-6f
#define MTOT (NB * SS)   // 32768 rows

typedef short bf16x8 __attribute__((ext_vector_type(8)));
typedef unsigned short u16x8 __attribute__((ext_vector_type(8)));
typedef float f32x4  __attribute__((ext_vector_type(4)));
typedef float f32x16 __attribute__((ext_vector_type(16)));
typedef int   i32x4  __attribute__((ext_vector_type(4)));
typedef int   i32x8  __attribute__((ext_vector_type(8)));
typedef unsigned char u8;

typedef __attribute__((address_space(1))) const unsigned int as1_u32;
typedef __attribute__((address_space(3))) unsigned int as3_u32;

__device__ __forceinline__ unsigned short f2bf(float f) {
  unsigned int u = __builtin_bit_cast(unsigned int, f);
  u = (u + 0x7FFFu + ((u >> 16) & 1u)) >> 16;
  return (unsigned short)u;
}
__device__ __forceinline__ u8 f2fp8(float f) {
  return (u8)(__builtin_amdgcn_cvt_pk_fp8_f32(f, f, 0, 0) & 0xFF);
}
__device__ __forceinline__ void dma16(const u8* src, u8* lds) {
  __builtin_amdgcn_global_load_lds((as1_u32*)src, (as3_u32*)lds, 16, 0, 0);
}
__device__ __forceinline__ float fast_exp2(float x) {
#if __has_builtin(__builtin_amdgcn_exp2f)
  return __builtin_amdgcn_exp2f(x);   // bare v_exp_f32
#else
  return exp2f(x);
#endif
}

// Counted-vmcnt barrier (T3/T4): wait only the OLDER prefetch DMAs, keep the
// newest N in flight across the barrier. sched_barrier pins ordering (rule 18).
#define CV_BARRIER(N)                                              \
  do {                                                             \
    asm volatile("s_waitcnt vmcnt(" #N ")" ::: "memory");          \
    __builtin_amdgcn_s_barrier();                                  \
    __builtin_amdgcn_sched_barrier(0);                             \
  } while (0)

// ---------------- GroupNorm stats, stage 1: coalesced partials ----------------
__global__ __launch_bounds__(256) void gn_stats_part_kernel(
    const float* __restrict__ x, float* __restrict__ part) {
  const int b = blockIdx.x >> 5, slice = blockIdx.x & 31;
  const int tid = threadIdx.x;
  const int g = tid & 31;            // group
  const int p8 = tid >> 5;           // pos sub-index 0..7
  const float* base = x + ((size_t)(b * SS + slice * 128 + p8) * CC + g * CPG);
  float s = 0.f, ss = 0.f;
#pragma unroll
  for (int it = 0; it < 16; it++) {
    const float4* p = (const float4*)(base + (size_t)it * 8 * CC);
    float4 a = p[0], c = p[1];
    s  += (a.x + a.y) + (a.z + a.w) + (c.x + c.y) + (c.z + c.w);
    ss += (a.x*a.x + a.y*a.y) + (a.z*a.z + a.w*a.w)
        + (c.x*c.x + c.y*c.y) + (c.z*c.z + c.w*c.w);
  }
  s  += __shfl_xor(s, 32);
  ss += __shfl_xor(ss, 32);
  __shared__ float lsum[4][32], lssum[4][32];
  const int wv = tid >> 6, lane = tid & 63;
  if (lane < 32) { lsum[wv][lane] = s; lssum[wv][lane] = ss; }
  __syncthreads();
  if (tid < 32) {
    float ts  = (lsum[0][tid] + lsum[1][tid]) + (lsum[2][tid] + lsum[3][tid]);
    float tss = (lssum[0][tid] + lssum[1][tid]) + (lssum[2][tid] + lssum[3][tid]);
    float* dst = part + ((size_t)(b * 32 + tid) * 32 + slice) * 2;
    dst[0] = ts; dst[1] = tss;
  }
}

// ---------------- Weight prep (+ fused gn_stats finalize at y==4) ----------------
__global__ __launch_bounds__(256) void prep_wt_kernel(
    const float* __restrict__ w0, const float* __restrict__ w1,
    const float* __restrict__ w2, const float* __restrict__ w3,
    unsigned short* __restrict__ wt,
    const float* __restrict__ part, float* __restrict__ stats) {
  __shared__ float t[64][68];
  if (blockIdx.y == 4) {
    if (blockIdx.x == 0) {
      const int bg = threadIdx.x;   // b*32+g, 0..255
      const float* src = part + (size_t)bg * 64;
      float s = 0.f, ss = 0.f;
#pragma unroll
      for (int sl = 0; sl < 32; sl++) { s += src[sl * 2]; ss += src[sl * 2 + 1]; }
      const float inv = 1.f / (float)(SS * CPG);
      float mean = s * inv;
      float var  = ss * inv - mean * mean;
      stats[bg * 2]     = mean;
      stats[bg * 2 + 1] = rsqrtf(var + EPSV);
    }
    return;
  }
  int which = blockIdx.y;
  const float* W = (which == 0) ? w0 : (which == 1) ? w1 : (which == 2) ? w2 : w3;
  int tx = (blockIdx.x & 3) * 64;
  int ty = (blockIdx.x >> 2) * 64;
  int tid = threadIdx.x;
  int row = tid >> 4;
  int col = (tid & 15) * 4;
#pragma unroll
  for (int i = 0; i < 4; i++) {
    float4 v = *(const float4*)(W + (size_t)(ty + row + i * 16) * CC + tx + col);
    *(float4*)(&t[row + i * 16][col]) = v;
  }
  __syncthreads();
#pragma unroll
  for (int i = 0; i < 4; i++) {
    int n = row + i * 16;
    ushort4 o;
    o.x = f2bf(t[col + 0][n]);
    o.y = f2bf(t[col + 1][n]);
    o.z = f2bf(t[col + 2][n]);
    o.w = f2bf(t[col + 3][n]);
    *(ushort4*)(wt + (size_t)which * CC * CC + (size_t)(tx + n) * CC + ty + col) = o;
  }
}

// ---------------- GroupNorm: normalize -> hn (bf16), 8 ch/thread ----------------
__global__ __launch_bounds__(256) void gn_norm_kernel(const float* __restrict__ x,
                                                      const float* __restrict__ stats,
                                                      const float* __restrict__ gamma,
                                                      const float* __restrict__ beta,
                                                      unsigned short* __restrict__ hn) {
  int i8 = blockIdx.x * 256 + threadIdx.x;
  int c8 = (i8 & 31) * 8;
  size_t row = (size_t)(i8 >> 5);
  int b = (int)(row >> 12);
  int sidx = (b * NG + (c8 >> 3)) * 2;
  float mean = stats[sidx], rstd = stats[sidx + 1];
  const float4* xp = (const float4*)(x + row * CC + c8);
  float4 v0 = xp[0], v1 = xp[1];
  const float4* gp = (const float4*)(gamma + c8);
  float4 g0 = gp[0], g1 = gp[1];
  const float4* bp = (const float4*)(beta + c8);
  float4 b0 = bp[0], b1 = bp[1];
  u16x8 o;
  o[0] = f2bf((v0.x - mean) * rstd * g0.x + b0.x);
  o[1] = f2bf((v0.y - mean) * rstd * g0.y + b0.y);
  o[2] = f2bf((v0.z - mean) * rstd * g0.z + b0.z);
  o[3] = f2bf((v0.w - mean) * rstd * g0.w + b0.w);
  o[4] = f2bf((v1.x - mean) * rstd * g1.x + b1.x);
  o[5] = f2bf((v1.y - mean) * rstd * g1.y + b1.y);
  o[6] = f2bf((v1.z - mean) * rstd * g1.z + b1.z);
  o[7] = f2bf((v1.w - mean) * rstd * g1.w + b1.w);
  *(u16x8*)(hn + row * CC + c8) = o;
}

// ---------------- GEMM v3: B-slab resident + A TRIPLE-buffer, counted vmcnt ----------------
// Tile 256(m) x 64(n), K-step 32, 4 waves each 64x64. Prefetch distance 2:
// at the barrier ending step s, only A(s+1) must be ready -> s_waitcnt vmcnt(4)
// keeps A(s+2)'s 4 DMAs in flight across the barrier (T3/T4; m218 counted-vs-
// drain0 = +38-73%). LDS = 3x16K A + 32K B = 80KB -> exactly 2 blocks/CU.

// QKV fused. Outputs: q fp8 (B,S,C) unscaled, k fp8 (B,S,C), v fp8 TRANSPOSED (B,C,S).
__global__ __launch_bounds__(256) void qkv_gemm_kernel(
    const unsigned short* __restrict__ A,
    const unsigned short* __restrict__ WT,
    const float* __restrict__ bq, const float* __restrict__ bk, const float* __restrict__ bv,
    u8* __restrict__ qo, u8* __restrict__ ko, u8* __restrict__ vt) {
  __shared__ __align__(1024) u8 smem[81920];
  u8* A0 = smem;             // 16KB each
  u8* A1 = smem + 16384;
  u8* A2 = smem + 32768;
  u8* Bs = smem + 49152;     // 32KB

  const int which = blockIdx.z;
  const u8* Bwb = (const u8*)(WT + (size_t)which * CC * CC);
  const float* bias = (which == 0) ? bq : (which == 1) ? bk : bv;

  const int m0 = blockIdx.x * 256;
  const int n0 = blockIdx.y * 64;
  const int tid = threadIdx.x;
  const int wave = tid >> 6, lane = tid & 63;
  const int l32 = lane & 31, h = lane >> 5;

  const u8* Ab = (const u8*)A;

  // A DMA map: issue i -> m = i*64 + (tid>>2), dest slot d = tid&3,
  //            src chunk = d ^ (m&3)   (involution; read uses same XOR)
  const int am = tid >> 2;
  const int aslot = tid & 3;
  const size_t asrc_row = (size_t)(m0 + am) * 512;
  const int asrc_ch = ((aslot ^ (am & 3)) << 4);
  // B DMA map: issue i -> n = i*8 + (tid>>5), d = tid&31, src chunk = d ^ (n&31)
  const int bn = tid >> 5;
  const int bslot = tid & 31;

  // prologue: whole B slab + A steps 0,1 (distance-2 pipeline fill)
#pragma unroll
  for (int i = 0; i < 8; i++) {
    int n = i * 8 + bn;
    dma16(Bwb + (size_t)(n0 + n) * 512 + ((bslot ^ (n & 31)) << 4),
          Bs + i * 4096 + tid * 16);
  }
#pragma unroll
  for (int i = 0; i < 4; i++)
    dma16(Ab + asrc_row + (size_t)i * 64 * 512 + asrc_ch, A0 + i * 4096 + tid * 16);
#pragma unroll
  for (int i = 0; i < 4; i++)
    dma16(Ab + asrc_row + (size_t)i * 64 * 512 + 64 + asrc_ch, A1 + i * 4096 + tid * 16);
  CV_BARRIER(4);   // B + A(0) ready; A(1) still in flight

  f32x16 acc[2][2] = {};
  const int arow0 = (wave * 64 + l32) * 64;
  const int nrow0 = l32 * 512;
  const int aswz = l32 & 3;
  const int bswz = l32;

#pragma unroll
  for (int s = 0; s < 8; ++s) {
    u8* const bufs[3] = {A0, A1, A2};
    u8* cur = bufs[s % 3];             // compile-time after unroll
    if (s + 2 < 8) {
      u8* nxt = bufs[(s + 2) % 3];
      size_t koff = (size_t)(s + 2) * 64;
#pragma unroll
      for (int i = 0; i < 4; i++)
        dma16(Ab + asrc_row + (size_t)i * 64 * 512 + koff + asrc_ch,
              nxt + i * 4096 + tid * 16);
    }
#pragma unroll
    for (int ks = 0; ks < 2; ks++) {
      bf16x8 af0 = *(const bf16x8*)(cur + arow0 + (((h + 2 * ks) ^ aswz) << 4));
      bf16x8 af1 = *(const bf16x8*)(cur + arow0 + 32 * 64 + (((h + 2 * ks) ^ aswz) << 4));
      bf16x8 bf0 = *(const bf16x8*)(Bs + nrow0 + (((s * 4 + h + 2 * ks) ^ bswz) << 4));
      bf16x8 bf1 = *(const bf16x8*)(Bs + nrow0 + 32 * 512 + (((s * 4 + h + 2 * ks) ^ bswz) << 4));
      acc[0][0] = __builtin_amdgcn_mfma_f32_32x32x16_bf16(af0, bf0, acc[0][0], 0, 0, 0);
      acc[0][1] = __builtin_amdgcn_mfma_f32_32x32x16_bf16(af0, bf1, acc[0][1], 0, 0, 0);
      acc[1][0] = __builtin_amdgcn_mfma_f32_32x32x16_bf16(af1, bf0, acc[1][0], 0, 0, 0);
      acc[1][1] = __builtin_amdgcn_mfma_f32_32x32x16_bf16(af1, bf1, acc[1][1], 0, 0, 0);
    }
    if (s < 6)      CV_BARRIER(4);   // A(s+1) ready; A(s+2) in flight
    else if (s < 7) CV_BARRIER(0);   // s==6: drain A(7), nothing newer
    // s==7: no barrier (epilogue reads registers only)
  }

  if (which < 2) {
    u8* out = (which == 0) ? qo : ko;
#pragma unroll
    for (int nt = 0; nt < 2; nt++) {
      int n = n0 + nt * 32 + l32;
      float bv_ = bias[n];
#pragma unroll
      for (int mt = 0; mt < 2; mt++)
#pragma unroll
        for (int r = 0; r < 16; r++) {
          int m = m0 + wave * 64 + mt * 32 + (r & 3) + 8 * (r >> 2) + 4 * h;
          out[(size_t)m * CC + n] = f2fp8(acc[mt][nt][r] + bv_);
        }
    }
  } else {
    int bb = m0 >> 12;
#pragma unroll
    for (int nt = 0; nt < 2; nt++) {
      int n = n0 + nt * 32 + l32;
      float bv_ = bias[n];
#pragma unroll
      for (int mt = 0; mt < 2; mt++)
#pragma unroll
        for (int g = 0; g < 4; g++) {
          int mg = m0 + wave * 64 + mt * 32 + g * 8 + 4 * h;
          int w = __builtin_amdgcn_cvt_pk_fp8_f32(acc[mt][nt][g*4+0] + bv_, acc[mt][nt][g*4+1] + bv_, 0, 0);
          w = __builtin_amdgcn_cvt_pk_fp8_f32(acc[mt][nt][g*4+2] + bv_, acc[mt][nt][g*4+3] + bv_, w, 1);
          *(unsigned int*)(vt + (size_t)bb * CC * SS + (size_t)n * SS + (mg & 4095)) = (unsigned int)w;
        }
    }
  }
}

// Final projection: out = ao @ wo + bo + x  (fp32 out)
__global__ __launch_bounds__(256) void out_gemm_kernel(
    const unsigned short* __restrict__ A,
    const unsigned short* __restrict__ WT,
    const float* __restrict__ bias,
    const float* __restrict__ residual,
    float* __restrict__ Of) {
  __shared__ __align__(1024) u8 smem[81920];
  u8* A0 = smem;
  u8* A1 = smem + 16384;
  u8* A2 = smem + 32768;
  u8* Bs = smem + 49152;

  const u8* Bwb = (const u8*)(WT + (size_t)3 * CC * CC);
  const int m0 = blockIdx.x * 256;
  const int n0 = blockIdx.y * 64;
  const int tid = threadIdx.x;
  const int wave = tid >> 6, lane = tid & 63;
  const int l32 = lane & 31, h = lane >> 5;

  const u8* Ab = (const u8*)A;
  const int am = tid >> 2;
  const int aslot = tid & 3;
  const size_t asrc_row = (size_t)(m0 + am) * 512;
  const int asrc_ch = ((aslot ^ (am & 3)) << 4);
  const int bn = tid >> 5;
  const int bslot = tid & 31;

#pragma unroll
  for (int i = 0; i < 8; i++) {
    int n = i * 8 + bn;
    dma16(Bwb + (size_t)(n0 + n) * 512 + ((bslot ^ (n & 31)) << 4),
          Bs + i * 4096 + tid * 16);
  }
#pragma unroll
  for (int i = 0; i < 4; i++)
    dma16(Ab + asrc_row + (size_t)i * 64 * 512 + asrc_ch, A0 + i * 4096 + tid * 16);
#pragma unroll
  for (int i = 0; i < 4; i++)
    dma16(Ab + asrc_row + (size_t)i * 64 * 512 + 64 + asrc_ch, A1 + i * 4096 + tid * 16);
  CV_BARRIER(4);

  f32x16 acc[2][2] = {};
  const int arow0 = (wave * 64 + l32) * 64;
  const int nrow0 = l32 * 512;
  const int aswz = l32 & 3;
  const int bswz = l32;

#pragma unroll
  for (int s = 0; s < 8; ++s) {
    u8* const bufs[3] = {A0, A1, A2};
    u8* cur = bufs[s % 3];
    if (s + 2 < 8) {
      u8* nxt = bufs[(s + 2) % 3];
      size_t koff = (size_t)(s + 2) * 64;
#pragma unroll
      for (int i = 0; i < 4; i++)
        dma16(Ab + asrc_row + (size_t)i * 64 * 512 + koff + asrc_ch,
              nxt + i * 4096 + tid * 16);
    }
#pragma unroll
    for (int ks = 0; ks < 2; ks++) {
      bf16x8 af0 = *(const bf16x8*)(cur + arow0 + (((h + 2 * ks) ^ aswz) << 4));
      bf16x8 af1 = *(const bf16x8*)(cur + arow0 + 32 * 64 + (((h + 2 * ks) ^ aswz) << 4));
      bf16x8 bf0 = *(const bf16x8*)(Bs + nrow0 + (((s * 4 + h + 2 * ks) ^ bswz) << 4));
      bf16x8 bf1 = *(const bf16x8*)(Bs + nrow0 + 32 * 512 + (((s * 4 + h + 2 * ks) ^ bswz) << 4));
      acc[0][0] = __builtin_amdgcn_mfma_f32_32x32x16_bf16(af0, bf0, acc[0][0], 0, 0, 0);
      acc[0][1] = __builtin_amdgcn_mfma_f32_32x32x16_bf16(af0, bf1, acc[0][1], 0, 0, 0);
      acc[1][0] = __builtin_amdgcn_mfma_f32_32x32x16_bf16(af1, bf0, acc[1][0], 0, 0, 0);
      acc[1][1] = __builtin_amdgcn_mfma_f32_32x32x16_bf16(af1, bf1, acc[1][1], 0, 0, 0);
    }
    if (s < 6)      CV_BARRIER(4);
    else if (s < 7) CV_BARRIER(0);
  }

#pragma unroll
  for (int nt = 0; nt < 2; nt++) {
    int n = n0 + nt * 32 + l32;
    float bv_ = bias[n];
#pragma unroll
    for (int mt = 0; mt < 2; mt++)
#pragma unroll
      for (int r = 0; r < 16; r++) {
        int m = m0 + wave * 64 + mt * 32 + (r & 3) + 8 * (r >> 2) + 4 * h;
        Of[(size_t)m * CC + n] = acc[mt][nt][r] + bv_ + residual[(size_t)m * CC + n];
      }
  }
}

// ---------------- Flash attention v3 (round-6 verbatim; 101.7us known-good) ----------------
// Register budget note: per-SIMD unified file = 512 regs/wave at 2 waves/SIMD.
// This kernel = 128 VGPR + 128 AGPR = exactly 256/wave. Do NOT raise min-waves
// and do NOT add live state. Occupancy is grid-capped at 2 blocks/CU (512 blocks);
// restructures to raise it (v4/v5/v6) all regressed -- local optimum.
#define BR 64

__global__ __launch_bounds__(256, 2) void flash_attn_kernel(
    const u8* __restrict__ Qg,   // (B,S,C) fp8, unscaled
    const u8* __restrict__ Kg,   // (B,S,C) fp8
    const u8* __restrict__ Vtg,  // (B,C,S) fp8
    unsigned short* __restrict__ Og) {
  __shared__ __align__(1024) u8 smem[65536 + 512];
  u8* KA  = smem;
  u8* KBb = smem + 16384;
  u8* VB  = smem + 32768;

  const int bid = blockIdx.x;
  const int b = bid & 7, q0 = (bid >> 3) * BR;
  const int tid = threadIdx.x;
  const int wave = tid >> 6, lane = tid & 63;
  const int l32 = lane & 31, h = lane >> 5;
  const int wm = wave >> 1, wn = wave & 1;   // wm: q-row half, wn: key half

  const u8* Qb  = Qg  + (size_t)b * SS * CC;
  const u8* Kb  = Kg  + (size_t)b * SS * CC;
  const u8* Vtb = Vtg + (size_t)b * CC * SS;

  const int kkey = tid >> 4, kc16 = tid & 15;
  const u8* ksrc0 = Kb + (size_t)kkey * CC + ((kc16 ^ (kkey & 15)) << 4);
  const int vch = tid >> 3;
  const int vs  = (tid & 7) ^ (vch & 7);
  const u8* vsrc0 = Vtb + (size_t)vch * SS + (vs << 4);

  i32x8 qf[4];
  {
    const u8* qrow = Qb + (size_t)(q0 + wm * 32 + l32) * CC + h * 32;
#pragma unroll
    for (int t = 0; t < 4; t++) qf[t] = *(const i32x8*)(qrow + t * 64);
  }

  f32x16 oacc[8] = {};
  float ll = 0.f;

#pragma unroll
  for (int i = 0; i < 4; i++)
    dma16(ksrc0 + (size_t)i * 16 * CC, KA + i * 4096 + tid * 16);

  const int kswz = l32 & 15;
  const int vswz = l32 & 7;

  for (int jp = 0; jp < 32; ++jp) {
    int w0[4], w1[4], o0[4];

    __syncthreads();
    {
      size_t krow = (size_t)jp * 128 + 64;
#pragma unroll
      for (int i = 0; i < 4; i++)
        dma16(ksrc0 + (krow + (size_t)i * 16) * CC, KBb + i * 4096 + tid * 16);
      size_t vbase = (size_t)jp * 128;
#pragma unroll
      for (int i = 0; i < 8; i++)
        dma16(vsrc0 + (size_t)i * 32 * SS + vbase, VB + i * 4096 + tid * 16);
    }
    {
      f32x16 sacc = {};
      const u8* kb = KA + (wn * 32 + l32) * 256;
      __builtin_amdgcn_s_setprio(1);
#pragma unroll
      for (int t = 0; t < 4; t++) {
        i32x4 r0 = *(const i32x4*)(kb + (((t * 4 + 2 * h)     ^ kswz) << 4));
        i32x4 r1 = *(const i32x4*)(kb + (((t * 4 + 2 * h + 1) ^ kswz) << 4));
        i32x8 kf = __builtin_shufflevector(r0, r1, 0, 1, 2, 3, 4, 5, 6, 7);
        sacc = __builtin_amdgcn_mfma_scale_f32_32x32x64_f8f6f4(
            kf, qf[t], sacc, 0, 0, 0, 0x7F7F7F7F, 0, 0x7F7F7F7F);
      }
      __builtin_amdgcn_s_setprio(0);
#pragma unroll
      for (int g = 0; g < 4; g++) {
        float p0 = fast_exp2(fminf(sacc[g * 4 + 0] * 0.09016844f, 7.213475f));
        float p1 = fast_exp2(fminf(sacc[g * 4 + 1] * 0.09016844f, 7.213475f));
        float p2 = fast_exp2(fminf(sacc[g * 4 + 2] * 0.09016844f, 7.213475f));
        float p3 = fast_exp2(fminf(sacc[g * 4 + 3] * 0.09016844f, 7.213475f));
        ll += (p0 + p1) + (p2 + p3);
        int wv_ = __builtin_amdgcn_cvt_pk_fp8_f32(p0, p1, 0, 0);
        w0[g] = __builtin_amdgcn_cvt_pk_fp8_f32(p2, p3, wv_, 1);
      }
#pragma unroll
      for (int g = 0; g < 4; g++) o0[g] = __shfl_xor(w0[g], 32);
    }

    __syncthreads();
    if (jp + 1 < 32) {
      size_t krow = (size_t)(jp + 1) * 128;
#pragma unroll
      for (int i = 0; i < 4; i++)
        dma16(ksrc0 + (krow + (size_t)i * 16) * CC, KA + i * 4096 + tid * 16);
    }
    {
      f32x16 sacc = {};
      const u8* kb = KBb + (wn * 32 + l32) * 256;
      __builtin_amdgcn_s_setprio(1);
#pragma unroll
      for (int t = 0; t < 4; t++) {
        i32x4 r0 = *(const i32x4*)(kb + (((t * 4 + 2 * h)     ^ kswz) << 4));
        i32x4 r1 = *(const i32x4*)(kb + (((t * 4 + 2 * h + 1) ^ kswz) << 4));
        i32x8 kf = __builtin_shufflevector(r0, r1, 0, 1, 2, 3, 4, 5, 6, 7);
        sacc = __builtin_amdgcn_mfma_scale_f32_32x32x64_f8f6f4(
            kf, qf[t], sacc, 0, 0, 0, 0x7F7F7F7F, 0, 0x7F7F7F7F);
      }
      __builtin_amdgcn_s_setprio(0);
#pragma unroll
      for (int g = 0; g < 4; g++) {
        float p0 = fast_exp2(fminf(sacc[g * 4 + 0] * 0.09016844f, 7.213475f));
        float p1 = fast_exp2(fminf(sacc[g * 4 + 1] * 0.09016844f, 7.213475f));
        float p2 = fast_exp2(fminf(sacc[g * 4 + 2] * 0.09016844f, 7.213475f));
        float p3 = fast_exp2(fminf(sacc[g * 4 + 3] * 0.09016844f, 7.213475f));
        ll += (p0 + p1) + (p2 + p3);
        int wv_ = __builtin_amdgcn_cvt_pk_fp8_f32(p0, p1, 0, 0);
        w1[g] = __builtin_amdgcn_cvt_pk_fp8_f32(p2, p3, wv_, 1);
      }
    }

    int pa_[8];
#pragma unroll
    for (int g = 0; g < 4; g++) {
      int o1 = __shfl_xor(w1[g], 32);
      pa_[2 * g]     = (h == 0) ? w0[g] : o1;
      pa_[2 * g + 1] = (h == 0) ? o0[g] : w1[g];
    }
    i32x8 pa = {pa_[0], pa_[1], pa_[2], pa_[3], pa_[4], pa_[5], pa_[6], pa_[7]};

    __builtin_amdgcn_s_setprio(1);
#pragma unroll
    for (int nt = 0; nt < 8; nt++) {
      const u8* vb = VB + (nt * 32 + l32) * 128;
      i32x4 r0 = *(const i32x4*)(vb + (((4 * h + 2 * wn)     ^ vswz) << 4));
      i32x4 r1 = *(const i32x4*)(vb + (((4 * h + 2 * wn + 1) ^ vswz) << 4));
      i32x8 vf = __builtin_shufflevector(r0, r1, 0, 1, 2, 3, 4, 5, 6, 7);
      oacc[nt] = __builtin_amdgcn_mfma_scale_f32_32x32x64_f8f6f4(
          pa, vf, oacc[nt], 0, 0, 0, 0x7F7F7F7F, 0, 0x7F7F7F7F);
    }
    __builtin_amdgcn_s_setprio(0);
  }

  __syncthreads();
  ll += __shfl_xor(ll, 32);
  float* Lred = (float*)(smem + 65536);
  if (h == 0) Lred[wn * 64 + wm * 32 + l32] = ll;

  float* scratch = (float*)smem;
  {
    float* z = scratch + (size_t)(wm * 2 + (1 - wn)) * 4096;
#pragma unroll
    for (int ntg = 0; ntg < 8; ntg++) {
      if ((ntg >> 2) != wn) {
        int nt = ntg & 3;
#pragma unroll
        for (int r = 0; r < 16; r++) {
          int row = (r & 3) + 8 * (r >> 2) + 4 * h;
          z[row * 128 + nt * 32 + l32] = oacc[ntg][r];
        }
      }
    }
  }
  __syncthreads();
  {
    const float* z = scratch + (size_t)(wm * 2 + wn) * 4096;
#pragma unroll
    for (int ntg = 0; ntg < 8; ntg++) {
      if ((ntg >> 2) == wn) {
        int nt = ntg & 3;
#pragma unroll
        for (int r = 0; r < 16; r++) {
          int row = (r & 3) + 8 * (r >> 2) + 4 * h;
          float inv = 1.f / (Lred[wm * 32 + row] + Lred[64 + wm * 32 + row]);
          float v = oacc[ntg][r] + z[row * 128 + nt * 32 + l32];
          Og[((size_t)b * SS + q0 + wm * 32 + row) * CC + wn * 128 + nt * 32 + l32]
              = f2bf(v * inv);
        }
      }
    }
  }
}

// ---------------- launch ----------------
extern "C" void kernel_launch(void* const* d_in, const int* in_sizes, int n_in,
                              void* d_out, int out_size, void* d_ws, size_t ws_size,
                              hipStream_t stream) {
  const float* x   = (const float*)d_in[0];
  const float* gsc = (const float*)d_in[1];
  const float* gbi = (const float*)d_in[2];
  const float* wq  = (const float*)d_in[3];
  const float* bq  = (const float*)d_in[4];
  const float* wk  = (const float*)d_in[5];
  const float* bk  = (const float*)d_in[6];
  const float* wv  = (const float*)d_in[7];
  const float* bv  = (const float*)d_in[8];
  const float* wo  = (const float*)d_in[9];
  const float* bo  = (const float*)d_in[10];
  float* out = (float*)d_out;

  // workspace: stats | wt(bf16) | hn(bf16) | ao(bf16) | q(fp8) | k(fp8) | vt(fp8)
  char* ws = (char*)d_ws;
  const size_t MAT = (size_t)MTOT * CC;
  float* stats        = (float*)ws;
  unsigned short* wt  = (unsigned short*)(ws + 4096);
  unsigned short* hn  = wt + (size_t)4 * CC * CC;
  unsigned short* ao  = hn + MAT;
  u8* q  = (u8*)(ao + MAT);
  u8* k  = q + MAT;
  u8* vt = k + MAT;

  // gn_stats partials (64KB) alias the ao region (written only by flash, later)
  float* part = (float*)ao;

  gn_stats_part_kernel<<<NB * NG, 256, 0, stream>>>(x, part);
  prep_wt_kernel<<<dim3(16, 5), 256, 0, stream>>>(wq, wk, wv, wo, wt, part, stats);
  gn_norm_kernel<<<(int)(MAT / 8 / 256), 256, 0, stream>>>(x, stats, gsc, gbi, hn);

  qkv_gemm_kernel<<<dim3(MTOT / 256, CC / 64, 3), 256, 0, stream>>>(
      hn, wt, bq, bk, bv, q, k, vt);

  flash_attn_kernel<<<NB * (SS / BR), 256, 0, stream>>>(q, k, vt, ao);

  out_gemm_kernel<<<dim3(MTOT / 256, CC / 64), 256, 0, stream>>>(ao, wt, bo, x, out);
}